// Round 1
// baseline (6659.947 us; speedup 1.0000x reference)
//
#include <hip/hip_runtime.h>
#include <math.h>

#define N_NODES 10000
#define N_EDGES 160000

__device__ __forceinline__ float silu_c(float x) {
    // 1.679 * x * sigmoid(x)
    return 1.679f * x / (1.0f + __expf(-x));
}

// ---------------- Kernel A: y = lin1(node_feats) ----------------
// y[n][0:128]          = x_s @ lin1_ws * l1
// y[n][128 + u*3 + c]  = (x_v @ lin1_wv)[u][c] * l1
__global__ __launch_bounds__(256) void node_lin1(
    const float* __restrict__ node_feats,
    const float* __restrict__ lin1_ws,
    const float* __restrict__ lin1_wv,
    float* __restrict__ y)
{
    __shared__ float xf[16 * 520];   // stride 520: breaks 4-way bank conflict
    const int blk = blockIdx.x;      // 625
    const int t = threadIdx.x;
    const int base = blk * 16;

    const float4* nf4 = (const float4*)(node_feats + (size_t)base * 512);
    #pragma unroll
    for (int r = 0; r < 8; r++) {
        int i4 = r * 256 + t;        // 0..2047
        int flat = i4 * 4;
        int n = flat >> 9;
        int off = flat & 511;
        *(float4*)&xf[n * 520 + off] = nf4[i4];
    }
    __syncthreads();

    const int n_loc = t >> 4;
    const int w0 = (t & 15) * 8;
    float as[8];
    float av[8][3];
    #pragma unroll
    for (int j = 0; j < 8; j++) { as[j] = 0.f; av[j][0] = 0.f; av[j][1] = 0.f; av[j][2] = 0.f; }

    const float* xrow = &xf[n_loc * 520];
    #pragma unroll 1
    for (int u = 0; u < 128; u++) {
        float xs  = xrow[u];
        float xv0 = xrow[128 + u*3 + 0];
        float xv1 = xrow[128 + u*3 + 1];
        float xv2 = xrow[128 + u*3 + 2];
        float ws[8], wv[8];
        *(float4*)&ws[0] = *(const float4*)&lin1_ws[u*128 + w0];
        *(float4*)&ws[4] = *(const float4*)&lin1_ws[u*128 + w0 + 4];
        *(float4*)&wv[0] = *(const float4*)&lin1_wv[u*128 + w0];
        *(float4*)&wv[4] = *(const float4*)&lin1_wv[u*128 + w0 + 4];
        #pragma unroll
        for (int j = 0; j < 8; j++) {
            as[j]    += xs  * ws[j];
            av[j][0] += xv0 * wv[j];
            av[j][1] += xv1 * wv[j];
            av[j][2] += xv2 * wv[j];
        }
    }

    const float l1 = 0.0883883476483f;  // 1/sqrt(128)
    const int node = base + n_loc;
    float* yrow = y + (size_t)node * 512;
    #pragma unroll
    for (int j = 0; j < 8; j++) {
        yrow[w0 + j] = as[j] * l1;
        yrow[128 + (w0 + j)*3 + 0] = av[j][0] * l1;
        yrow[128 + (w0 + j)*3 + 1] = av[j][1] * l1;
        yrow[128 + (w0 + j)*3 + 2] = av[j][2] * l1;
    }
}

// ---------------- Kernel B: edge FC MLP + gather + scatter ----------------
// acc[n][0:128]   += w_ss*qs*a_s * inv          (mid_s0)
// acc[n][128:256] += w_vv*(qv.a_v)/sqrt3 * inv  (mid_s1)
// acc[n][256+u*3+c]        += w_sv*qs*a_v[c]*inv     (mid_v2, u<128)
// acc[n][256+(128+u)*3+c]  += w_vs*qv[c]*a_s*inv     (mid_v3)
__global__ __launch_bounds__(256) void edge_kernel(
    const float* __restrict__ edge_feats,
    const float* __restrict__ edge_attrs,
    const int*   __restrict__ edge_index,
    const float* __restrict__ fc_w0,
    const float* __restrict__ fc_w1,
    const float* __restrict__ fc_w2,
    const float* __restrict__ y,
    float* __restrict__ acc)
{
    __shared__ float ef_lds[32 * 9];
    __shared__ float h0_lds[32 * 65];
    __shared__ float h1_lds[32 * 65];

    const int blk = blockIdx.x;      // 5000
    const int t = threadIdx.x;
    const int e_loc = t >> 3;        // 0..31
    const int p = t & 7;             // 0..7
    const int eb0 = blk * 32;

    {   // stage edge_feats (32 edges x 8)
        float v = edge_feats[(size_t)eb0 * 8 + t];
        ef_lds[(t >> 3) * 9 + (t & 7)] = v;
    }
    __syncthreads();

    // phase 1: h0 = silu_c(ef @ w0 / sqrt(8)), thread -> i in [8p, 8p+8)
    {
        float a0[8];
        #pragma unroll
        for (int i = 0; i < 8; i++) a0[i] = 0.f;
        const float* efr = &ef_lds[e_loc * 9];
        #pragma unroll
        for (int k = 0; k < 8; k++) {
            float ek = efr[k];
            float w[8];
            *(float4*)&w[0] = *(const float4*)&fc_w0[k*64 + p*8];
            *(float4*)&w[4] = *(const float4*)&fc_w0[k*64 + p*8 + 4];
            #pragma unroll
            for (int i = 0; i < 8; i++) a0[i] += ek * w[i];
        }
        const float is8 = 0.35355339059f;  // 1/sqrt(8)
        #pragma unroll
        for (int i = 0; i < 8; i++)
            h0_lds[e_loc * 65 + p*8 + i] = silu_c(a0[i] * is8);
    }
    __syncthreads();

    // phase 1b: h1 = silu_c(h0 @ w1 / 8)
    {
        float a1[8];
        #pragma unroll
        for (int i = 0; i < 8; i++) a1[i] = 0.f;
        const float* h0r = &h0_lds[e_loc * 65];
        #pragma unroll 1
        for (int j = 0; j < 64; j++) {
            float hj = h0r[j];
            float w[8];
            *(float4*)&w[0] = *(const float4*)&fc_w1[j*64 + p*8];
            *(float4*)&w[4] = *(const float4*)&fc_w1[j*64 + p*8 + 4];
            #pragma unroll
            for (int i = 0; i < 8; i++) a1[i] += hj * w[i];
        }
        #pragma unroll
        for (int i = 0; i < 8; i++)
            h1_lds[e_loc * 65 + p*8 + i] = silu_c(a1[i] * 0.125f);
    }
    __syncthreads();

    // phase 2: w = (h1 @ w2)/8; thread owns o = m*128 + k*32 + p*4 + i
    float wreg[64];
    #pragma unroll
    for (int i = 0; i < 64; i++) wreg[i] = 0.f;
    {
        const float* h1r = &h1_lds[e_loc * 65];
        #pragma unroll 1
        for (int j = 0; j < 64; j++) {
            float hj = h1r[j];
            const float* w2r = fc_w2 + j*512 + p*4;
            #pragma unroll
            for (int mk = 0; mk < 16; mk++) {
                int m = mk >> 2, k = mk & 3;
                float4 wv = *(const float4*)&w2r[m*128 + k*32];
                wreg[mk*4+0] += hj * wv.x;
                wreg[mk*4+1] += hj * wv.y;
                wreg[mk*4+2] += hj * wv.z;
                wreg[mk*4+3] += hj * wv.w;
            }
        }
        #pragma unroll
        for (int i = 0; i < 64; i++) wreg[i] *= 0.125f;
    }

    // phase 3: gather y[src], scatter into acc[dst]
    const int eb = eb0 + e_loc;
    const int dst = edge_index[eb];
    const int src = edge_index[N_EDGES + eb];
    const float a_s = edge_attrs[eb*4 + 0];
    const float av0 = edge_attrs[eb*4 + 1];
    const float av1 = edge_attrs[eb*4 + 2];
    const float av2 = edge_attrs[eb*4 + 3];
    const float* yq = y + (size_t)src * 512;
    float* accd = acc + (size_t)dst * 1024;
    const float inv = 0.25f;                       // 1/sqrt(16)
    const float s1c = 0.57735026919f * 0.25f;      // inv/sqrt(3)

    #pragma unroll
    for (int k = 0; k < 4; k++) {
        const int u0 = k*32 + p*4;
        float qs[4];
        *(float4*)&qs[0] = *(const float4*)&yq[u0];
        float qv[12];
        *(float4*)&qv[0] = *(const float4*)&yq[128 + u0*3];
        *(float4*)&qv[4] = *(const float4*)&yq[128 + u0*3 + 4];
        *(float4*)&qv[8] = *(const float4*)&yq[128 + u0*3 + 8];
        #pragma unroll
        for (int i = 0; i < 4; i++) {
            const int u = u0 + i;
            float wss = wreg[(0  + k)*4 + i];
            float wsv = wreg[(4  + k)*4 + i];
            float wvs = wreg[(8  + k)*4 + i];
            float wvv = wreg[(12 + k)*4 + i];
            float q0 = qv[i*3+0], q1 = qv[i*3+1], q2 = qv[i*3+2];

            atomicAdd(accd + u, wss * qs[i] * a_s * inv);
            float dot = q0*av0 + q1*av1 + q2*av2;
            atomicAdd(accd + 128 + u, wvv * dot * s1c);
            float tsv = wsv * qs[i] * inv;
            atomicAdd(accd + 256 + u*3 + 0, tsv * av0);
            atomicAdd(accd + 256 + u*3 + 1, tsv * av1);
            atomicAdd(accd + 256 + u*3 + 2, tsv * av2);
            float tvs = wvs * a_s * inv;
            atomicAdd(accd + 256 + (128 + u)*3 + 0, tvs * q0);
            atomicAdd(accd + 256 + (128 + u)*3 + 1, tvs * q1);
            atomicAdd(accd + 256 + (128 + u)*3 + 2, tvs * q2);
        }
    }
}

// ---------------- Kernel C: out = lin2(acc)*l2 + sc ----------------
__global__ __launch_bounds__(256) void node_out(
    const float* __restrict__ node_feats,
    const float* __restrict__ node_attrs,
    const float* __restrict__ lin2_ws,
    const float* __restrict__ lin2_wv,
    const float* __restrict__ sc_ws,
    const float* __restrict__ sc_wv,
    const float* __restrict__ acc,
    float* __restrict__ out)
{
    __shared__ float sv[16 * 1024];  // 64 KB exactly
    const int blk = blockIdx.x;      // 625
    const int t = threadIdx.x;
    const int base = blk * 16;

    const float4* acc4 = (const float4*)(acc + (size_t)base * 1024);
    #pragma unroll
    for (int r = 0; r < 16; r++) {
        int i4 = r * 256 + t;        // 0..4095
        *(float4*)&sv[i4 * 4] = acc4[i4];
    }
    __syncthreads();

    const int n_loc = t >> 4;
    const int w0 = (t & 15) * 8;
    const int node = base + n_loc;

    float attr[10];
    #pragma unroll
    for (int v = 0; v < 10; v++) attr[v] = node_attrs[node*10 + v];

    float os[8];
    float ov[8][3];
    #pragma unroll
    for (int j = 0; j < 8; j++) { os[j] = 0.f; ov[j][0] = 0.f; ov[j][1] = 0.f; ov[j][2] = 0.f; }

    // --- sc einsum part: sum_u sum_v x*attr[v]*sc_w[u,v,w] ---
    const float* xrow = node_feats + (size_t)node * 512;
    #pragma unroll 1
    for (int u = 0; u < 128; u++) {
        float xs  = xrow[u];
        float xv0 = xrow[128 + u*3 + 0];
        float xv1 = xrow[128 + u*3 + 1];
        float xv2 = xrow[128 + u*3 + 2];
        #pragma unroll
        for (int v = 0; v < 10; v++) {
            float a = attr[v];
            float cs = xs * a;
            float c0 = xv0 * a, c1 = xv1 * a, c2 = xv2 * a;
            int widx = (u*10 + v)*128 + w0;
            float ws[8], wv[8];
            *(float4*)&ws[0] = *(const float4*)&sc_ws[widx];
            *(float4*)&ws[4] = *(const float4*)&sc_ws[widx + 4];
            *(float4*)&wv[0] = *(const float4*)&sc_wv[widx];
            *(float4*)&wv[4] = *(const float4*)&sc_wv[widx + 4];
            #pragma unroll
            for (int j = 0; j < 8; j++) {
                os[j]    += cs * ws[j];
                ov[j][0] += c0 * wv[j];
                ov[j][1] += c1 * wv[j];
                ov[j][2] += c2 * wv[j];
            }
        }
    }
    const float sc_norm = 0.02795084972f;  // 1/sqrt(1280)
    #pragma unroll
    for (int j = 0; j < 8; j++) {
        os[j] *= sc_norm;
        ov[j][0] *= sc_norm; ov[j][1] *= sc_norm; ov[j][2] *= sc_norm;
    }

    // --- lin2 part ---
    const float l2 = 0.0625f;  // 1/sqrt(256)
    const float* srow = &sv[n_loc * 1024];
    #pragma unroll 1
    for (int j = 0; j < 256; j++) {
        float sj = srow[j] * l2;
        float v0 = srow[256 + j*3 + 0] * l2;
        float v1 = srow[256 + j*3 + 1] * l2;
        float v2 = srow[256 + j*3 + 2] * l2;
        float ws[8], wv[8];
        *(float4*)&ws[0] = *(const float4*)&lin2_ws[j*128 + w0];
        *(float4*)&ws[4] = *(const float4*)&lin2_ws[j*128 + w0 + 4];
        *(float4*)&wv[0] = *(const float4*)&lin2_wv[j*128 + w0];
        *(float4*)&wv[4] = *(const float4*)&lin2_wv[j*128 + w0 + 4];
        #pragma unroll
        for (int jj = 0; jj < 8; jj++) {
            os[jj]    += sj * ws[jj];
            ov[jj][0] += v0 * wv[jj];
            ov[jj][1] += v1 * wv[jj];
            ov[jj][2] += v2 * wv[jj];
        }
    }

    float* orow = out + (size_t)node * 512;
    #pragma unroll
    for (int j = 0; j < 8; j++) {
        orow[w0 + j] = os[j];
        orow[128 + (w0 + j)*3 + 0] = ov[j][0];
        orow[128 + (w0 + j)*3 + 1] = ov[j][1];
        orow[128 + (w0 + j)*3 + 2] = ov[j][2];
    }
}

extern "C" void kernel_launch(void* const* d_in, const int* in_sizes, int n_in,
                              void* d_out, int out_size, void* d_ws, size_t ws_size,
                              hipStream_t stream) {
    const float* node_feats = (const float*)d_in[0];
    const float* node_attrs = (const float*)d_in[1];
    const float* edge_feats = (const float*)d_in[2];
    const float* edge_attrs = (const float*)d_in[3];
    const int*   edge_index = (const int*)  d_in[4];
    const float* lin1_ws    = (const float*)d_in[5];
    const float* lin1_wv    = (const float*)d_in[6];
    const float* fc_w0      = (const float*)d_in[7];
    const float* fc_w1      = (const float*)d_in[8];
    const float* fc_w2      = (const float*)d_in[9];
    const float* lin2_ws    = (const float*)d_in[10];
    const float* lin2_wv    = (const float*)d_in[11];
    const float* sc_ws      = (const float*)d_in[12];
    const float* sc_wv      = (const float*)d_in[13];
    float* out = (float*)d_out;

    float* y   = (float*)d_ws;                       // N*512 floats
    float* acc = y + (size_t)N_NODES * 512;          // N*1024 floats

    hipMemsetAsync(acc, 0, (size_t)N_NODES * 1024 * sizeof(float), stream);
    hipLaunchKernelGGL(node_lin1, dim3(625), dim3(256), 0, stream,
                       node_feats, lin1_ws, lin1_wv, y);
    hipLaunchKernelGGL(edge_kernel, dim3(5000), dim3(256), 0, stream,
                       edge_feats, edge_attrs, edge_index,
                       fc_w0, fc_w1, fc_w2, y, acc);
    hipLaunchKernelGGL(node_out, dim3(625), dim3(256), 0, stream,
                       node_feats, node_attrs, lin2_ws, lin2_wv,
                       sc_ws, sc_wv, acc, out);
}

// Round 2
// 1818.900 us; speedup vs baseline: 3.6615x; 3.6615x over previous
//
#include <hip/hip_runtime.h>
#include <hip/hip_bf16.h>
#include <math.h>

#define N_NODES 10000
#define N_EDGES 160000

__device__ __forceinline__ float silu_c(float x) {
    return 1.679f * x / (1.0f + __expf(-x));
}
__device__ __forceinline__ float bf2f(unsigned short u) {
    return __uint_as_float(((unsigned)u) << 16);
}

// ---------------- Kernel A: y = lin1(node_feats), layout y[n][u][4]={s,v0,v1,v2} ----------------
__global__ __launch_bounds__(256) void node_lin1(
    const float* __restrict__ node_feats,
    const float* __restrict__ lin1_ws,
    const float* __restrict__ lin1_wv,
    float* __restrict__ y)
{
    __shared__ float xf[16 * 520];
    const int blk = blockIdx.x;      // 625
    const int t = threadIdx.x;
    const int base = blk * 16;

    const float4* nf4 = (const float4*)(node_feats + (size_t)base * 512);
    #pragma unroll
    for (int r = 0; r < 8; r++) {
        int i4 = r * 256 + t;
        int flat = i4 * 4;
        int n = flat >> 9;
        int off = flat & 511;
        *(float4*)&xf[n * 520 + off] = nf4[i4];
    }
    __syncthreads();

    const int n_loc = t >> 4;
    const int w0 = (t & 15) * 8;
    float as[8];
    float av[8][3];
    #pragma unroll
    for (int j = 0; j < 8; j++) { as[j] = 0.f; av[j][0] = 0.f; av[j][1] = 0.f; av[j][2] = 0.f; }

    const float* xrow = &xf[n_loc * 520];
    #pragma unroll 1
    for (int u = 0; u < 128; u++) {
        float xs  = xrow[u];
        float xv0 = xrow[128 + u*3 + 0];
        float xv1 = xrow[128 + u*3 + 1];
        float xv2 = xrow[128 + u*3 + 2];
        float ws[8], wv[8];
        *(float4*)&ws[0] = *(const float4*)&lin1_ws[u*128 + w0];
        *(float4*)&ws[4] = *(const float4*)&lin1_ws[u*128 + w0 + 4];
        *(float4*)&wv[0] = *(const float4*)&lin1_wv[u*128 + w0];
        *(float4*)&wv[4] = *(const float4*)&lin1_wv[u*128 + w0 + 4];
        #pragma unroll
        for (int j = 0; j < 8; j++) {
            as[j]    += xs  * ws[j];
            av[j][0] += xv0 * wv[j];
            av[j][1] += xv1 * wv[j];
            av[j][2] += xv2 * wv[j];
        }
    }

    const float l1 = 0.0883883476483f;  // 1/sqrt(128)
    const int node = base + n_loc;
    float* yrow = y + (size_t)node * 512;
    #pragma unroll
    for (int j = 0; j < 8; j++) {
        float4 o = make_float4(as[j] * l1, av[j][0] * l1, av[j][1] * l1, av[j][2] * l1);
        *(float4*)&yrow[(w0 + j) * 4] = o;
    }
}

// ---------------- CSR build ----------------
__global__ __launch_bounds__(256) void hist_kernel(const int* __restrict__ edge_index,
                                                   int* __restrict__ deg) {
    int e = blockIdx.x * 256 + threadIdx.x;
    if (e < N_EDGES) atomicAdd(&deg[edge_index[e]], 1);
}

__global__ __launch_bounds__(1024) void scan_kernel(const int* __restrict__ deg,
                                                    int* __restrict__ row_start,
                                                    int* __restrict__ cursor) {
    __shared__ int wsum[16];
    __shared__ int carry_s;
    const int t = threadIdx.x;        // 0..1023
    const int lane = t & 63, w = t >> 6;
    if (t == 0) carry_s = 0;
    __syncthreads();
    for (int chunk = 0; chunk < 10; chunk++) {
        int idx = chunk * 1024 + t;
        int v = (idx < N_NODES) ? deg[idx] : 0;
        int x = v;
        #pragma unroll
        for (int off = 1; off < 64; off <<= 1) {
            int yv = __shfl_up(x, off, 64);
            if (lane >= off) x += yv;
        }
        if (lane == 63) wsum[w] = x;
        __syncthreads();
        int wpre = 0;
        for (int i = 0; i < w; i++) wpre += wsum[i];
        int incl = x + wpre + carry_s;
        int excl = incl - v;
        if (idx < N_NODES) { row_start[idx] = excl; cursor[idx] = excl; }
        __syncthreads();
        if (t == 1023) carry_s = incl;
        __syncthreads();
    }
    if (t == 0) row_start[N_NODES] = carry_s;
}

__global__ __launch_bounds__(256) void scatter_kernel(const int* __restrict__ edge_index,
                                                      int* __restrict__ cursor,
                                                      int* __restrict__ edge_list) {
    int e = blockIdx.x * 256 + threadIdx.x;
    if (e < N_EDGES) {
        int pos = atomicAdd(&cursor[edge_index[e]], 1);
        edge_list[pos] = e;
    }
}

// ---------------- Kernel B1: per-edge MLP -> packed bf16 w ----------------
// w_e[e][u][4] = bf16{w_ss, w_sv, w_vs, w_vv}[u]
__global__ __launch_bounds__(256) void edge_w_kernel(
    const float* __restrict__ edge_feats,
    const float* __restrict__ fc_w0,
    const float* __restrict__ fc_w1,
    const float* __restrict__ fc_w2,
    __hip_bfloat16* __restrict__ w_e)
{
    __shared__ float ef_lds[32 * 9];
    __shared__ float h0_lds[32 * 65];
    __shared__ float h1_lds[32 * 65];

    const int blk = blockIdx.x;      // 5000
    const int t = threadIdx.x;
    const int e_loc = t >> 3;        // 0..31
    const int p = t & 7;             // 0..7
    const int eb0 = blk * 32;

    {
        float v = edge_feats[(size_t)eb0 * 8 + t];
        ef_lds[(t >> 3) * 9 + (t & 7)] = v;
    }
    __syncthreads();

    {
        float a0[8];
        #pragma unroll
        for (int i = 0; i < 8; i++) a0[i] = 0.f;
        const float* efr = &ef_lds[e_loc * 9];
        #pragma unroll
        for (int k = 0; k < 8; k++) {
            float ek = efr[k];
            float w[8];
            *(float4*)&w[0] = *(const float4*)&fc_w0[k*64 + p*8];
            *(float4*)&w[4] = *(const float4*)&fc_w0[k*64 + p*8 + 4];
            #pragma unroll
            for (int i = 0; i < 8; i++) a0[i] += ek * w[i];
        }
        const float is8 = 0.35355339059f;
        #pragma unroll
        for (int i = 0; i < 8; i++)
            h0_lds[e_loc * 65 + p*8 + i] = silu_c(a0[i] * is8);
    }
    __syncthreads();

    {
        float a1[8];
        #pragma unroll
        for (int i = 0; i < 8; i++) a1[i] = 0.f;
        const float* h0r = &h0_lds[e_loc * 65];
        #pragma unroll 1
        for (int j = 0; j < 64; j++) {
            float hj = h0r[j];
            float w[8];
            *(float4*)&w[0] = *(const float4*)&fc_w1[j*64 + p*8];
            *(float4*)&w[4] = *(const float4*)&fc_w1[j*64 + p*8 + 4];
            #pragma unroll
            for (int i = 0; i < 8; i++) a1[i] += hj * w[i];
        }
        #pragma unroll
        for (int i = 0; i < 8; i++)
            h1_lds[e_loc * 65 + p*8 + i] = silu_c(a1[i] * 0.125f);
    }
    __syncthreads();

    float wreg[64];
    #pragma unroll
    for (int i = 0; i < 64; i++) wreg[i] = 0.f;
    {
        const float* h1r = &h1_lds[e_loc * 65];
        #pragma unroll 1
        for (int j = 0; j < 64; j++) {
            float hj = h1r[j];
            const float* w2r = fc_w2 + j*512 + p*4;
            #pragma unroll
            for (int mk = 0; mk < 16; mk++) {
                int m = mk >> 2, k = mk & 3;
                float4 wv = *(const float4*)&w2r[m*128 + k*32];
                wreg[mk*4+0] += hj * wv.x;
                wreg[mk*4+1] += hj * wv.y;
                wreg[mk*4+2] += hj * wv.z;
                wreg[mk*4+3] += hj * wv.w;
            }
        }
        #pragma unroll
        for (int i = 0; i < 64; i++) wreg[i] *= 0.125f;
    }

    // pack + store: thread owns u = k*32 + p*4 + i
    const int eb = eb0 + e_loc;
    __hip_bfloat16* wr = w_e + (size_t)eb * 512;
    #pragma unroll
    for (int k = 0; k < 4; k++) {
        #pragma unroll
        for (int i = 0; i < 4; i++) {
            int u = k*32 + p*4 + i;
            union { ushort4 u4; __hip_bfloat16 h[4]; } pk;
            pk.h[0] = __float2bfloat16(wreg[(0  + k)*4 + i]);  // w_ss
            pk.h[1] = __float2bfloat16(wreg[(4  + k)*4 + i]);  // w_sv
            pk.h[2] = __float2bfloat16(wreg[(8  + k)*4 + i]);  // w_vs
            pk.h[3] = __float2bfloat16(wreg[(12 + k)*4 + i]);  // w_vv
            *(ushort4*)(wr + u*4) = pk.u4;
        }
    }
}

// ---------------- Kernel B2: per-node gather (no atomics) ----------------
__global__ __launch_bounds__(256) void gather_kernel(
    const int* __restrict__ row_start,
    const int* __restrict__ edge_list,
    const int* __restrict__ edge_index,
    const float* __restrict__ edge_attrs,
    const __hip_bfloat16* __restrict__ w_e,
    const float* __restrict__ y,
    float* __restrict__ acc)
{
    const int t = threadIdx.x;
    const int half = t >> 7;
    const int u = t & 127;
    const int n = blockIdx.x * 2 + half;   // 5000 blocks
    const int sbeg = row_start[n];
    const int send = row_start[n + 1];

    float aS0 = 0.f, aS1 = 0.f;
    float aV2x = 0.f, aV2y = 0.f, aV2z = 0.f;
    float aV3x = 0.f, aV3y = 0.f, aV3z = 0.f;

    const unsigned short* wbase = (const unsigned short*)w_e;
    for (int i = sbeg; i < send; i++) {
        int e = edge_list[i];
        int src = edge_index[N_EDGES + e];
        ushort4 wb = *(const ushort4*)(wbase + (size_t)e * 512 + u * 4);
        float4 q  = *(const float4*)(y + (size_t)src * 512 + u * 4);
        float4 ea = *(const float4*)(edge_attrs + (size_t)e * 4);
        float wss = bf2f(wb.x), wsv = bf2f(wb.y), wvs = bf2f(wb.z), wvv = bf2f(wb.w);
        aS0 += wss * q.x * ea.x;
        aS1 += wvv * (q.y*ea.y + q.z*ea.z + q.w*ea.w);
        float tsv = wsv * q.x;
        aV2x += tsv * ea.y; aV2y += tsv * ea.z; aV2z += tsv * ea.w;
        float tvs = wvs * ea.x;
        aV3x += tvs * q.y; aV3y += tvs * q.z; aV3z += tvs * q.w;
    }

    const float inv = 0.25f;                 // 1/sqrt(16)
    const float s1c = 0.57735026919f * 0.25f;
    float* a = acc + (size_t)n * 1024;
    a[u] = aS0 * inv;
    a[128 + u] = aS1 * s1c;
    a[256 + u*3 + 0] = aV2x * inv;
    a[256 + u*3 + 1] = aV2y * inv;
    a[256 + u*3 + 2] = aV2z * inv;
    a[256 + (128 + u)*3 + 0] = aV3x * inv;
    a[256 + (128 + u)*3 + 1] = aV3y * inv;
    a[256 + (128 + u)*3 + 2] = aV3z * inv;
}

// ---------------- Fallback atomic edge kernel (only if ws too small) ----------------
__global__ __launch_bounds__(256) void edge_kernel_atomic(
    const float* __restrict__ edge_feats,
    const float* __restrict__ edge_attrs,
    const int*   __restrict__ edge_index,
    const float* __restrict__ fc_w0,
    const float* __restrict__ fc_w1,
    const float* __restrict__ fc_w2,
    const float* __restrict__ y,
    float* __restrict__ acc)
{
    __shared__ float ef_lds[32 * 9];
    __shared__ float h0_lds[32 * 65];
    __shared__ float h1_lds[32 * 65];

    const int blk = blockIdx.x;
    const int t = threadIdx.x;
    const int e_loc = t >> 3;
    const int p = t & 7;
    const int eb0 = blk * 32;

    {
        float v = edge_feats[(size_t)eb0 * 8 + t];
        ef_lds[(t >> 3) * 9 + (t & 7)] = v;
    }
    __syncthreads();
    {
        float a0[8];
        #pragma unroll
        for (int i = 0; i < 8; i++) a0[i] = 0.f;
        const float* efr = &ef_lds[e_loc * 9];
        #pragma unroll
        for (int k = 0; k < 8; k++) {
            float ek = efr[k];
            float w[8];
            *(float4*)&w[0] = *(const float4*)&fc_w0[k*64 + p*8];
            *(float4*)&w[4] = *(const float4*)&fc_w0[k*64 + p*8 + 4];
            #pragma unroll
            for (int i = 0; i < 8; i++) a0[i] += ek * w[i];
        }
        const float is8 = 0.35355339059f;
        #pragma unroll
        for (int i = 0; i < 8; i++)
            h0_lds[e_loc * 65 + p*8 + i] = silu_c(a0[i] * is8);
    }
    __syncthreads();
    {
        float a1[8];
        #pragma unroll
        for (int i = 0; i < 8; i++) a1[i] = 0.f;
        const float* h0r = &h0_lds[e_loc * 65];
        #pragma unroll 1
        for (int j = 0; j < 64; j++) {
            float hj = h0r[j];
            float w[8];
            *(float4*)&w[0] = *(const float4*)&fc_w1[j*64 + p*8];
            *(float4*)&w[4] = *(const float4*)&fc_w1[j*64 + p*8 + 4];
            #pragma unroll
            for (int i = 0; i < 8; i++) a1[i] += hj * w[i];
        }
        #pragma unroll
        for (int i = 0; i < 8; i++)
            h1_lds[e_loc * 65 + p*8 + i] = silu_c(a1[i] * 0.125f);
    }
    __syncthreads();

    float wreg[64];
    #pragma unroll
    for (int i = 0; i < 64; i++) wreg[i] = 0.f;
    {
        const float* h1r = &h1_lds[e_loc * 65];
        #pragma unroll 1
        for (int j = 0; j < 64; j++) {
            float hj = h1r[j];
            const float* w2r = fc_w2 + j*512 + p*4;
            #pragma unroll
            for (int mk = 0; mk < 16; mk++) {
                int m = mk >> 2, k = mk & 3;
                float4 wv = *(const float4*)&w2r[m*128 + k*32];
                wreg[mk*4+0] += hj * wv.x;
                wreg[mk*4+1] += hj * wv.y;
                wreg[mk*4+2] += hj * wv.z;
                wreg[mk*4+3] += hj * wv.w;
            }
        }
        #pragma unroll
        for (int i = 0; i < 64; i++) wreg[i] *= 0.125f;
    }

    const int eb = eb0 + e_loc;
    const int dst = edge_index[eb];
    const int src = edge_index[N_EDGES + eb];
    const float a_s = edge_attrs[eb*4 + 0];
    const float av0 = edge_attrs[eb*4 + 1];
    const float av1 = edge_attrs[eb*4 + 2];
    const float av2 = edge_attrs[eb*4 + 3];
    const float* yq = y + (size_t)src * 512;
    float* accd = acc + (size_t)dst * 1024;
    const float inv = 0.25f;
    const float s1c = 0.57735026919f * 0.25f;

    #pragma unroll
    for (int k = 0; k < 4; k++) {
        const int u0 = k*32 + p*4;
        #pragma unroll
        for (int i = 0; i < 4; i++) {
            const int u = u0 + i;
            float4 q = *(const float4*)&yq[u * 4];  // {s, v0, v1, v2}
            float wss = wreg[(0  + k)*4 + i];
            float wsv = wreg[(4  + k)*4 + i];
            float wvs = wreg[(8  + k)*4 + i];
            float wvv = wreg[(12 + k)*4 + i];

            atomicAdd(accd + u, wss * q.x * a_s * inv);
            float dot = q.y*av0 + q.z*av1 + q.w*av2;
            atomicAdd(accd + 128 + u, wvv * dot * s1c);
            float tsv = wsv * q.x * inv;
            atomicAdd(accd + 256 + u*3 + 0, tsv * av0);
            atomicAdd(accd + 256 + u*3 + 1, tsv * av1);
            atomicAdd(accd + 256 + u*3 + 2, tsv * av2);
            float tvs = wvs * a_s * inv;
            atomicAdd(accd + 256 + (128 + u)*3 + 0, tvs * q.y);
            atomicAdd(accd + 256 + (128 + u)*3 + 1, tvs * q.z);
            atomicAdd(accd + 256 + (128 + u)*3 + 2, tvs * q.w);
        }
    }
}

// ---------------- Kernel C: out = lin2(acc)*l2 + sc ----------------
__global__ __launch_bounds__(256) void node_out(
    const float* __restrict__ node_feats,
    const float* __restrict__ node_attrs,
    const float* __restrict__ lin2_ws,
    const float* __restrict__ lin2_wv,
    const float* __restrict__ sc_ws,
    const float* __restrict__ sc_wv,
    const float* __restrict__ acc,
    float* __restrict__ out)
{
    __shared__ float sv[16 * 1024];
    const int blk = blockIdx.x;      // 625
    const int t = threadIdx.x;
    const int base = blk * 16;

    const float4* acc4 = (const float4*)(acc + (size_t)base * 1024);
    #pragma unroll
    for (int r = 0; r < 16; r++) {
        int i4 = r * 256 + t;
        *(float4*)&sv[i4 * 4] = acc4[i4];
    }
    __syncthreads();

    const int n_loc = t >> 4;
    const int w0 = (t & 15) * 8;
    const int node = base + n_loc;

    float attr[10];
    #pragma unroll
    for (int v = 0; v < 10; v++) attr[v] = node_attrs[node*10 + v];

    float os[8];
    float ov[8][3];
    #pragma unroll
    for (int j = 0; j < 8; j++) { os[j] = 0.f; ov[j][0] = 0.f; ov[j][1] = 0.f; ov[j][2] = 0.f; }

    const float* xrow = node_feats + (size_t)node * 512;
    #pragma unroll 1
    for (int u = 0; u < 128; u++) {
        float xs  = xrow[u];
        float xv0 = xrow[128 + u*3 + 0];
        float xv1 = xrow[128 + u*3 + 1];
        float xv2 = xrow[128 + u*3 + 2];
        #pragma unroll
        for (int v = 0; v < 10; v++) {
            float a = attr[v];
            float cs = xs * a;
            float c0 = xv0 * a, c1 = xv1 * a, c2 = xv2 * a;
            int widx = (u*10 + v)*128 + w0;
            float ws[8], wv[8];
            *(float4*)&ws[0] = *(const float4*)&sc_ws[widx];
            *(float4*)&ws[4] = *(const float4*)&sc_ws[widx + 4];
            *(float4*)&wv[0] = *(const float4*)&sc_wv[widx];
            *(float4*)&wv[4] = *(const float4*)&sc_wv[widx + 4];
            #pragma unroll
            for (int j = 0; j < 8; j++) {
                os[j]    += cs * ws[j];
                ov[j][0] += c0 * wv[j];
                ov[j][1] += c1 * wv[j];
                ov[j][2] += c2 * wv[j];
            }
        }
    }
    const float sc_norm = 0.02795084972f;
    #pragma unroll
    for (int j = 0; j < 8; j++) {
        os[j] *= sc_norm;
        ov[j][0] *= sc_norm; ov[j][1] *= sc_norm; ov[j][2] *= sc_norm;
    }

    const float l2 = 0.0625f;
    const float* srow = &sv[n_loc * 1024];
    #pragma unroll 1
    for (int j = 0; j < 256; j++) {
        float sj = srow[j] * l2;
        float v0 = srow[256 + j*3 + 0] * l2;
        float v1 = srow[256 + j*3 + 1] * l2;
        float v2 = srow[256 + j*3 + 2] * l2;
        float ws[8], wv[8];
        *(float4*)&ws[0] = *(const float4*)&lin2_ws[j*128 + w0];
        *(float4*)&ws[4] = *(const float4*)&lin2_ws[j*128 + w0 + 4];
        *(float4*)&wv[0] = *(const float4*)&lin2_wv[j*128 + w0];
        *(float4*)&wv[4] = *(const float4*)&lin2_wv[j*128 + w0 + 4];
        #pragma unroll
        for (int jj = 0; jj < 8; jj++) {
            os[jj]    += sj * ws[jj];
            ov[jj][0] += v0 * wv[jj];
            ov[jj][1] += v1 * wv[jj];
            ov[jj][2] += v2 * wv[jj];
        }
    }

    float* orow = out + (size_t)node * 512;
    #pragma unroll
    for (int j = 0; j < 8; j++) {
        orow[w0 + j] = os[j];
        orow[128 + (w0 + j)*3 + 0] = ov[j][0];
        orow[128 + (w0 + j)*3 + 1] = ov[j][1];
        orow[128 + (w0 + j)*3 + 2] = ov[j][2];
    }
}

extern "C" void kernel_launch(void* const* d_in, const int* in_sizes, int n_in,
                              void* d_out, int out_size, void* d_ws, size_t ws_size,
                              hipStream_t stream) {
    const float* node_feats = (const float*)d_in[0];
    const float* node_attrs = (const float*)d_in[1];
    const float* edge_feats = (const float*)d_in[2];
    const float* edge_attrs = (const float*)d_in[3];
    const int*   edge_index = (const int*)  d_in[4];
    const float* lin1_ws    = (const float*)d_in[5];
    const float* lin1_wv    = (const float*)d_in[6];
    const float* fc_w0      = (const float*)d_in[7];
    const float* fc_w1      = (const float*)d_in[8];
    const float* fc_w2      = (const float*)d_in[9];
    const float* lin2_ws    = (const float*)d_in[10];
    const float* lin2_wv    = (const float*)d_in[11];
    const float* sc_ws      = (const float*)d_in[12];
    const float* sc_wv      = (const float*)d_in[13];
    float* out = (float*)d_out;

    // workspace layout
    float* y   = (float*)d_ws;                        //  5,120,000 f32 (20.48 MB)
    float* acc = y + (size_t)N_NODES * 512;           // 10,240,000 f32 (40.96 MB)
    __hip_bfloat16* w_e = (__hip_bfloat16*)(acc + (size_t)N_NODES * 1024); // 81,920,000 bf16
    int* deg       = (int*)(w_e + (size_t)N_EDGES * 512);
    int* row_start = deg + 10016;
    int* cursor    = row_start + 10016;
    int* edge_list = cursor + 10016;
    const size_t need = (size_t)(5120000 + 10240000) * 4 + (size_t)81920000 * 2
                      + (size_t)(10016 * 3 + N_EDGES) * 4;

    hipLaunchKernelGGL(node_lin1, dim3(625), dim3(256), 0, stream,
                       node_feats, lin1_ws, lin1_wv, y);

    if (ws_size >= need) {
        // CSR path: no global atomics on the fat accumulator
        hipMemsetAsync(deg, 0, (size_t)N_NODES * sizeof(int), stream);
        hipLaunchKernelGGL(hist_kernel, dim3(625), dim3(256), 0, stream, edge_index, deg);
        hipLaunchKernelGGL(scan_kernel, dim3(1), dim3(1024), 0, stream, deg, row_start, cursor);
        hipLaunchKernelGGL(scatter_kernel, dim3(625), dim3(256), 0, stream,
                           edge_index, cursor, edge_list);
        hipLaunchKernelGGL(edge_w_kernel, dim3(5000), dim3(256), 0, stream,
                           edge_feats, fc_w0, fc_w1, fc_w2, w_e);
        hipLaunchKernelGGL(gather_kernel, dim3(5000), dim3(256), 0, stream,
                           row_start, edge_list, edge_index, edge_attrs, w_e, y, acc);
    } else {
        hipMemsetAsync(acc, 0, (size_t)N_NODES * 1024 * sizeof(float), stream);
        hipLaunchKernelGGL(edge_kernel_atomic, dim3(5000), dim3(256), 0, stream,
                           edge_feats, edge_attrs, edge_index,
                           fc_w0, fc_w1, fc_w2, y, acc);
    }

    hipLaunchKernelGGL(node_out, dim3(625), dim3(256), 0, stream,
                       node_feats, node_attrs, lin2_ws, lin2_wv,
                       sc_ws, sc_wv, acc, out);
}

// Round 3
// 1088.562 us; speedup vs baseline: 6.1181x; 1.6709x over previous
//
#include <hip/hip_runtime.h>
#include <hip/hip_bf16.h>
#include <math.h>

#define N_NODES 10000
#define N_EDGES 160000
#define SBLK 157            // ceil(10000/64) s-GEMM blocks
#define VBLK 469            // ceil(30000/64) v-GEMM blocks

typedef __attribute__((ext_vector_type(8))) short short8x;
typedef __attribute__((ext_vector_type(4))) float floatx4;

union S8 { short8x v; unsigned short u[8]; uint4 q; };

__device__ __forceinline__ unsigned short f2bf(float x) {
    unsigned int u = __float_as_uint(x);
    return (unsigned short)((u + 0x7fffu + ((u >> 16) & 1u)) >> 16);
}
__device__ __forceinline__ float bf2f(unsigned short u) {
    return __uint_as_float(((unsigned)u) << 16);
}
__device__ __forceinline__ float silu_c(float x) {
    return 1.679f * x / (1.0f + __expf(-x));
}

// ---------------- Kernel A: y = lin1(node_feats), layout y[n][u][4]={s,v0,v1,v2} ----------------
__global__ __launch_bounds__(256) void node_lin1(
    const float* __restrict__ node_feats,
    const float* __restrict__ lin1_ws,
    const float* __restrict__ lin1_wv,
    float* __restrict__ y)
{
    __shared__ float xf[16 * 520];
    const int blk = blockIdx.x;      // 625
    const int t = threadIdx.x;
    const int base = blk * 16;

    const float4* nf4 = (const float4*)(node_feats + (size_t)base * 512);
    #pragma unroll
    for (int r = 0; r < 8; r++) {
        int i4 = r * 256 + t;
        int flat = i4 * 4;
        int n = flat >> 9;
        int off = flat & 511;
        *(float4*)&xf[n * 520 + off] = nf4[i4];
    }
    __syncthreads();

    const int n_loc = t >> 4;
    const int w0 = (t & 15) * 8;
    float as[8];
    float av[8][3];
    #pragma unroll
    for (int j = 0; j < 8; j++) { as[j] = 0.f; av[j][0] = 0.f; av[j][1] = 0.f; av[j][2] = 0.f; }

    const float* xrow = &xf[n_loc * 520];
    #pragma unroll 1
    for (int u = 0; u < 128; u++) {
        float xs  = xrow[u];
        float xv0 = xrow[128 + u*3 + 0];
        float xv1 = xrow[128 + u*3 + 1];
        float xv2 = xrow[128 + u*3 + 2];
        float ws[8], wvv[8];
        *(float4*)&ws[0] = *(const float4*)&lin1_ws[u*128 + w0];
        *(float4*)&ws[4] = *(const float4*)&lin1_ws[u*128 + w0 + 4];
        *(float4*)&wvv[0] = *(const float4*)&lin1_wv[u*128 + w0];
        *(float4*)&wvv[4] = *(const float4*)&lin1_wv[u*128 + w0 + 4];
        #pragma unroll
        for (int j = 0; j < 8; j++) {
            as[j]    += xs  * ws[j];
            av[j][0] += xv0 * wvv[j];
            av[j][1] += xv1 * wvv[j];
            av[j][2] += xv2 * wvv[j];
        }
    }

    const float l1 = 0.0883883476483f;  // 1/sqrt(128)
    const int node = base + n_loc;
    float* yrow = y + (size_t)node * 512;
    #pragma unroll
    for (int j = 0; j < 8; j++) {
        float4 o = make_float4(as[j] * l1, av[j][0] * l1, av[j][1] * l1, av[j][2] * l1);
        *(float4*)&yrow[(w0 + j) * 4] = o;
    }
}

// ---------------- CSR build ----------------
__global__ __launch_bounds__(256) void hist_kernel(const int* __restrict__ edge_index,
                                                   int* __restrict__ deg) {
    int e = blockIdx.x * 256 + threadIdx.x;
    if (e < N_EDGES) atomicAdd(&deg[edge_index[e]], 1);
}

__global__ __launch_bounds__(1024) void scan_kernel(const int* __restrict__ deg,
                                                    int* __restrict__ row_start,
                                                    int* __restrict__ cursor) {
    __shared__ int wsum[16];
    __shared__ int carry_s;
    const int t = threadIdx.x;        // 0..1023
    const int lane = t & 63, w = t >> 6;
    if (t == 0) carry_s = 0;
    __syncthreads();
    for (int chunk = 0; chunk < 10; chunk++) {
        int idx = chunk * 1024 + t;
        int v = (idx < N_NODES) ? deg[idx] : 0;
        int x = v;
        #pragma unroll
        for (int off = 1; off < 64; off <<= 1) {
            int yv = __shfl_up(x, off, 64);
            if (lane >= off) x += yv;
        }
        if (lane == 63) wsum[w] = x;
        __syncthreads();
        int wpre = 0;
        for (int i = 0; i < w; i++) wpre += wsum[i];
        int incl = x + wpre + carry_s;
        int excl = incl - v;
        if (idx < N_NODES) { row_start[idx] = excl; cursor[idx] = excl; }
        __syncthreads();
        if (t == 1023) carry_s = incl;
        __syncthreads();
    }
    if (t == 0) row_start[N_NODES] = carry_s;
}

__global__ __launch_bounds__(256) void scatter_kernel(const int* __restrict__ edge_index,
                                                      int* __restrict__ cursor,
                                                      int* __restrict__ edge_list) {
    int e = blockIdx.x * 256 + threadIdx.x;
    if (e < N_EDGES) {
        int pos = atomicAdd(&cursor[edge_index[e]], 1);
        edge_list[pos] = e;
    }
}

// ---------------- Kernel B1: per-edge MLP -> packed bf16 w ----------------
__global__ __launch_bounds__(256) void edge_w_kernel(
    const float* __restrict__ edge_feats,
    const float* __restrict__ fc_w0,
    const float* __restrict__ fc_w1,
    const float* __restrict__ fc_w2,
    __hip_bfloat16* __restrict__ w_e)
{
    __shared__ float ef_lds[32 * 9];
    __shared__ float h0_lds[32 * 65];
    __shared__ float h1_lds[32 * 65];

    const int blk = blockIdx.x;      // 5000
    const int t = threadIdx.x;
    const int e_loc = t >> 3;        // 0..31
    const int p = t & 7;             // 0..7
    const int eb0 = blk * 32;

    {
        float v = edge_feats[(size_t)eb0 * 8 + t];
        ef_lds[(t >> 3) * 9 + (t & 7)] = v;
    }
    __syncthreads();

    {
        float a0[8];
        #pragma unroll
        for (int i = 0; i < 8; i++) a0[i] = 0.f;
        const float* efr = &ef_lds[e_loc * 9];
        #pragma unroll
        for (int k = 0; k < 8; k++) {
            float ek = efr[k];
            float w[8];
            *(float4*)&w[0] = *(const float4*)&fc_w0[k*64 + p*8];
            *(float4*)&w[4] = *(const float4*)&fc_w0[k*64 + p*8 + 4];
            #pragma unroll
            for (int i = 0; i < 8; i++) a0[i] += ek * w[i];
        }
        const float is8 = 0.35355339059f;
        #pragma unroll
        for (int i = 0; i < 8; i++)
            h0_lds[e_loc * 65 + p*8 + i] = silu_c(a0[i] * is8);
    }
    __syncthreads();

    {
        float a1[8];
        #pragma unroll
        for (int i = 0; i < 8; i++) a1[i] = 0.f;
        const float* h0r = &h0_lds[e_loc * 65];
        #pragma unroll 1
        for (int j = 0; j < 64; j++) {
            float hj = h0r[j];
            float w[8];
            *(float4*)&w[0] = *(const float4*)&fc_w1[j*64 + p*8];
            *(float4*)&w[4] = *(const float4*)&fc_w1[j*64 + p*8 + 4];
            #pragma unroll
            for (int i = 0; i < 8; i++) a1[i] += hj * w[i];
        }
        #pragma unroll
        for (int i = 0; i < 8; i++)
            h1_lds[e_loc * 65 + p*8 + i] = silu_c(a1[i] * 0.125f);
    }
    __syncthreads();

    float wreg[64];
    #pragma unroll
    for (int i = 0; i < 64; i++) wreg[i] = 0.f;
    {
        const float* h1r = &h1_lds[e_loc * 65];
        #pragma unroll 1
        for (int j = 0; j < 64; j++) {
            float hj = h1r[j];
            const float* w2r = fc_w2 + j*512 + p*4;
            #pragma unroll
            for (int mk = 0; mk < 16; mk++) {
                int m = mk >> 2, k = mk & 3;
                float4 wv = *(const float4*)&w2r[m*128 + k*32];
                wreg[mk*4+0] += hj * wv.x;
                wreg[mk*4+1] += hj * wv.y;
                wreg[mk*4+2] += hj * wv.z;
                wreg[mk*4+3] += hj * wv.w;
            }
        }
        #pragma unroll
        for (int i = 0; i < 64; i++) wreg[i] *= 0.125f;
    }

    const int eb = eb0 + e_loc;
    __hip_bfloat16* wr = w_e + (size_t)eb * 512;
    #pragma unroll
    for (int k = 0; k < 4; k++) {
        #pragma unroll
        for (int i = 0; i < 4; i++) {
            int u = k*32 + p*4 + i;
            S8 pk;
            pk.u[0] = f2bf(wreg[(0  + k)*4 + i]);  // w_ss
            pk.u[1] = f2bf(wreg[(4  + k)*4 + i]);  // w_sv
            pk.u[2] = f2bf(wreg[(8  + k)*4 + i]);  // w_vs
            pk.u[3] = f2bf(wreg[(12 + k)*4 + i]);  // w_vv
            *(ushort4*)((unsigned short*)wr + u*4) = make_ushort4(pk.u[0], pk.u[1], pk.u[2], pk.u[3]);
        }
    }
}

// ---------------- Kernel B2: per-node gather (no atomics) ----------------
__global__ __launch_bounds__(256) void gather_kernel(
    const int* __restrict__ row_start,
    const int* __restrict__ edge_list,
    const int* __restrict__ edge_index,
    const float* __restrict__ edge_attrs,
    const __hip_bfloat16* __restrict__ w_e,
    const float* __restrict__ y,
    float* __restrict__ acc)
{
    const int t = threadIdx.x;
    const int half = t >> 7;
    const int u = t & 127;
    const int n = blockIdx.x * 2 + half;   // 5000 blocks
    const int sbeg = row_start[n];
    const int send = row_start[n + 1];

    float aS0 = 0.f, aS1 = 0.f;
    float aV2x = 0.f, aV2y = 0.f, aV2z = 0.f;
    float aV3x = 0.f, aV3y = 0.f, aV3z = 0.f;

    const unsigned short* wbase = (const unsigned short*)w_e;
    for (int i = sbeg; i < send; i++) {
        int e = edge_list[i];
        int src = edge_index[N_EDGES + e];
        ushort4 wb = *(const ushort4*)(wbase + (size_t)e * 512 + u * 4);
        float4 qv  = *(const float4*)(y + (size_t)src * 512 + u * 4);
        float4 ea = *(const float4*)(edge_attrs + (size_t)e * 4);
        float wss = bf2f(wb.x), wsv = bf2f(wb.y), wvs = bf2f(wb.z), wvv = bf2f(wb.w);
        aS0 += wss * qv.x * ea.x;
        aS1 += wvv * (qv.y*ea.y + qv.z*ea.z + qv.w*ea.w);
        float tsv = wsv * qv.x;
        aV2x += tsv * ea.y; aV2y += tsv * ea.z; aV2z += tsv * ea.w;
        float tvs = wvs * ea.x;
        aV3x += tvs * qv.y; aV3y += tvs * qv.z; aV3z += tvs * qv.w;
    }

    const float inv = 0.25f;                 // 1/sqrt(16)
    const float s1c = 0.57735026919f * 0.25f;
    float* a = acc + (size_t)n * 1024;
    a[u] = aS0 * inv;
    a[128 + u] = aS1 * s1c;
    a[256 + u*3 + 0] = aV2x * inv;
    a[256 + u*3 + 1] = aV2y * inv;
    a[256 + u*3 + 2] = aV2z * inv;
    a[256 + (128 + u)*3 + 0] = aV3x * inv;
    a[256 + (128 + u)*3 + 1] = aV3y * inv;
    a[256 + (128 + u)*3 + 2] = aV3z * inv;
}

// ---------------- pack_b: B matrices -> bf16, MFMA B-fragment order ----------------
// K-order: k < 1280: k = v*128 + u  -> sc_w[(u*10+v)*128 + n]; k >= 1280: lin2_w[k-1280][n]
// slot layout: [mat(2)][kstep(48)][nf(8)][lane(64)] of ushort8;
// slot (ks, nf, lane) holds B[k=ks*32+(lane>>4)*8+j][n=nf*16+(lane&15)], j=0..7
__global__ __launch_bounds__(256) void pack_b_kernel(
    const float* __restrict__ sc_ws, const float* __restrict__ lin2_ws,
    const float* __restrict__ sc_wv, const float* __restrict__ lin2_wv,
    unsigned short* __restrict__ b_pre)
{
    int id = blockIdx.x * 256 + threadIdx.x;     // 0..49151
    int mat = id / 24576;
    int slot = id - mat * 24576;
    int ks = slot >> 9;
    int rr = slot & 511;
    int lane = rr & 63;
    int quad = lane >> 4;
    int n = ((rr >> 6) << 4) + (lane & 15);
    const float* sc  = mat ? sc_wv  : sc_ws;
    const float* lin = mat ? lin2_wv : lin2_ws;
    S8 pk;
    #pragma unroll
    for (int j = 0; j < 8; j++) {
        int k = ks * 32 + quad * 8 + j;
        float w;
        if (k < 1280) {
            int u = k & 127, v = k >> 7;
            w = sc[(u * 10 + v) * 128 + n];
        } else {
            w = lin[(k - 1280) * 128 + n];
        }
        pk.u[j] = f2bf(w);
    }
    *(uint4*)(b_pre + (size_t)id * 8) = pk.q;
}

// ---------------- node_out as MFMA GEMM ----------------
// s-blocks (bid<SBLK): rows = nodes, B = Ws.  v-blocks: rows = comp*10000+node, B = Wv.
// out[n,w] = sum_k z[n,k] * B[k,w];  z folds sc_norm (x*attr part) and l2 (acc part).
__global__ __launch_bounds__(256) void node_out_mfma(
    const float* __restrict__ node_feats,
    const float* __restrict__ node_attrs,
    const float* __restrict__ acc,
    const unsigned short* __restrict__ b_pre,
    float* __restrict__ out)
{
    __shared__ short8x Al[256];     // 64 rows x 32 k, fragment-order packed (4 KB)
    const int bid = blockIdx.x;
    const int t = threadIdx.x;
    const int lane = t & 63;
    const int wv = t >> 6;
    const bool is_s = (bid < SBLK);

    // A-generation assignment: thread -> (row r in tile, k-quad q)
    const int r = t >> 2;
    const int q = t & 3;
    int node, comp, st;
    if (is_s) {
        int R = bid * 64 + r;
        node = (R < N_NODES) ? R : 0;
        comp = 0; st = 1;
    } else {
        int Rg = (bid - SBLK) * 64 + r;
        if (Rg >= 3 * N_NODES) Rg = 0;
        comp = Rg / N_NODES;
        node = Rg - comp * N_NODES;
        st = 3;
    }
    const float* px = is_s ? (node_feats + (size_t)node * 512)
                           : (node_feats + (size_t)node * 512 + 128 + comp);
    const float* pa = is_s ? (acc + (size_t)node * 1024)
                           : (acc + (size_t)node * 1024 + 256 + comp);
    const float* pattr = node_attrs + node * 10;

    const int a_slot = ((r >> 4) << 6) + (q << 4) + (r & 15);
    const uint4* bfrag_base = (const uint4*)(b_pre) + (is_s ? 0 : 24576);

    const float sc_norm = 0.02795084972f;   // 1/sqrt(1280)
    const float l2 = 0.0625f;               // 1/sqrt(256)

    floatx4 c[4][2];
    #pragma unroll
    for (int af = 0; af < 4; af++) {
        c[af][0] = (floatx4){0.f, 0.f, 0.f, 0.f};
        c[af][1] = (floatx4){0.f, 0.f, 0.f, 0.f};
    }

    for (int ks = 0; ks < 48; ks++) {
        // B-fragments straight from global (pre-packed, L2-resident, coalesced 16B/lane)
        S8 b0, b1;
        b0.q = bfrag_base[ks*512 + (wv*2+0)*64 + lane];
        b1.q = bfrag_base[ks*512 + (wv*2+1)*64 + lane];

        __syncthreads();   // protect Al from previous iteration's readers
        {
            int k0 = ks * 32 + q * 8;
            S8 pk;
            if (k0 < 1280) {
                int u0 = k0 & 127;
                int v  = k0 >> 7;          // uniform over the 8-slot
                float att = pattr[v] * sc_norm;
                #pragma unroll
                for (int j = 0; j < 8; j++)
                    pk.u[j] = f2bf(px[(u0 + j) * st] * att);
            } else {
                int j2 = k0 - 1280;
                #pragma unroll
                for (int j = 0; j < 8; j++)
                    pk.u[j] = f2bf(pa[(j2 + j) * st] * l2);
            }
            Al[a_slot] = pk.v;
        }
        __syncthreads();

        short8x a0 = Al[lane];
        short8x a1 = Al[64 + lane];
        short8x a2 = Al[128 + lane];
        short8x a3 = Al[192 + lane];
        c[0][0] = __builtin_amdgcn_mfma_f32_16x16x32_bf16(a0, b0.v, c[0][0], 0, 0, 0);
        c[0][1] = __builtin_amdgcn_mfma_f32_16x16x32_bf16(a0, b1.v, c[0][1], 0, 0, 0);
        c[1][0] = __builtin_amdgcn_mfma_f32_16x16x32_bf16(a1, b0.v, c[1][0], 0, 0, 0);
        c[1][1] = __builtin_amdgcn_mfma_f32_16x16x32_bf16(a1, b1.v, c[1][1], 0, 0, 0);
        c[2][0] = __builtin_amdgcn_mfma_f32_16x16x32_bf16(a2, b0.v, c[2][0], 0, 0, 0);
        c[2][1] = __builtin_amdgcn_mfma_f32_16x16x32_bf16(a2, b1.v, c[2][1], 0, 0, 0);
        c[3][0] = __builtin_amdgcn_mfma_f32_16x16x32_bf16(a3, b0.v, c[3][0], 0, 0, 0);
        c[3][1] = __builtin_amdgcn_mfma_f32_16x16x32_bf16(a3, b1.v, c[3][1], 0, 0, 0);
    }

    // epilogue: C/D layout col=lane&15, row=(lane>>4)*4+reg
    const int m = lane & 15;
    const int rq = (lane >> 4) * 4;
    if (is_s) {
        const int n0 = bid * 64;
        #pragma unroll
        for (int af = 0; af < 4; af++) {
            #pragma unroll
            for (int i = 0; i < 4; i++) {
                int n = n0 + af*16 + rq + i;
                if (n < N_NODES) {
                    out[(size_t)n*512 + wv*32 + m]      = c[af][0][i];
                    out[(size_t)n*512 + wv*32 + 16 + m] = c[af][1][i];
                }
            }
        }
    } else {
        const int r0 = (bid - SBLK) * 64;
        #pragma unroll
        for (int af = 0; af < 4; af++) {
            #pragma unroll
            for (int i = 0; i < 4; i++) {
                int Rg = r0 + af*16 + rq + i;
                if (Rg < 3 * N_NODES) {
                    int cc = Rg / N_NODES;
                    int nn = Rg - cc * N_NODES;
                    float* po = out + (size_t)nn*512 + 128 + cc;
                    po[(wv*32 + m)*3]      = c[af][0][i];
                    po[(wv*32 + 16 + m)*3] = c[af][1][i];
                }
            }
        }
    }
}

extern "C" void kernel_launch(void* const* d_in, const int* in_sizes, int n_in,
                              void* d_out, int out_size, void* d_ws, size_t ws_size,
                              hipStream_t stream) {
    const float* node_feats = (const float*)d_in[0];
    const float* node_attrs = (const float*)d_in[1];
    const float* edge_feats = (const float*)d_in[2];
    const float* edge_attrs = (const float*)d_in[3];
    const int*   edge_index = (const int*)  d_in[4];
    const float* lin1_ws    = (const float*)d_in[5];
    const float* lin1_wv    = (const float*)d_in[6];
    const float* fc_w0      = (const float*)d_in[7];
    const float* fc_w1      = (const float*)d_in[8];
    const float* fc_w2      = (const float*)d_in[9];
    const float* lin2_ws    = (const float*)d_in[10];
    const float* lin2_wv    = (const float*)d_in[11];
    const float* sc_ws      = (const float*)d_in[12];
    const float* sc_wv      = (const float*)d_in[13];
    float* out = (float*)d_out;

    // workspace layout
    float* y   = (float*)d_ws;                        //  5,120,000 f32
    float* acc = y + (size_t)N_NODES * 512;           // 10,240,000 f32
    __hip_bfloat16* w_e = (__hip_bfloat16*)(acc + (size_t)N_NODES * 1024); // 81,920,000 bf16
    int* deg       = (int*)(w_e + (size_t)N_EDGES * 512);
    int* row_start = deg + 10016;
    int* cursor    = row_start + 10016;
    int* edge_list = cursor + 10016;
    unsigned short* b_pre = (unsigned short*)(edge_list + N_EDGES); // 2*24576*8 ushorts (786 KB)
    const size_t need = (size_t)(5120000 + 10240000) * 4 + (size_t)81920000 * 2
                      + (size_t)(10016 * 3 + N_EDGES) * 4 + (size_t)2 * 24576 * 8 * 2;
    if (ws_size < need) return;   // cannot run without scratch (has never triggered)

    hipLaunchKernelGGL(pack_b_kernel, dim3(192), dim3(256), 0, stream,
                       sc_ws, lin2_ws, sc_wv, lin2_wv, b_pre);
    hipLaunchKernelGGL(node_lin1, dim3(625), dim3(256), 0, stream,
                       node_feats, lin1_ws, lin1_wv, y);

    hipMemsetAsync(deg, 0, (size_t)N_NODES * sizeof(int), stream);
    hipLaunchKernelGGL(hist_kernel, dim3(625), dim3(256), 0, stream, edge_index, deg);
    hipLaunchKernelGGL(scan_kernel, dim3(1), dim3(1024), 0, stream, deg, row_start, cursor);
    hipLaunchKernelGGL(scatter_kernel, dim3(625), dim3(256), 0, stream,
                       edge_index, cursor, edge_list);
    hipLaunchKernelGGL(edge_w_kernel, dim3(5000), dim3(256), 0, stream,
                       edge_feats, fc_w0, fc_w1, fc_w2, w_e);
    hipLaunchKernelGGL(gather_kernel, dim3(5000), dim3(256), 0, stream,
                       row_start, edge_list, edge_index, edge_attrs, w_e, y, acc);

    hipLaunchKernelGGL(node_out_mfma, dim3(SBLK + VBLK), dim3(256), 0, stream,
                       node_feats, node_attrs, acc, b_pre, out);
}

// Round 4
// 681.213 us; speedup vs baseline: 9.7766x; 1.5980x over previous
//
#include <hip/hip_runtime.h>
#include <hip/hip_bf16.h>
#include <math.h>

#define N_NODES 10000
#define N_EDGES 160000
#define SBLK 157            // ceil(10000/64) s-GEMM blocks
#define VBLK 469            // ceil(30000/64) v-GEMM blocks

typedef __attribute__((ext_vector_type(8))) short short8x;
typedef __attribute__((ext_vector_type(4))) float floatx4;

union S8 { short8x v; unsigned short u[8]; uint4 q; };

__device__ __forceinline__ unsigned short f2bf(float x) {
    unsigned int u = __float_as_uint(x);
    return (unsigned short)((u + 0x7fffu + ((u >> 16) & 1u)) >> 16);
}
__device__ __forceinline__ float bf2f(unsigned short u) {
    return __uint_as_float(((unsigned)u) << 16);
}
__device__ __forceinline__ float silu_c(float x) {
    return 1.679f * x / (1.0f + __expf(-x));
}

// ---------------- Kernel A: y = lin1(node_feats), layout y[n][u][4]={s,v0,v1,v2} ----------------
__global__ __launch_bounds__(256) void node_lin1(
    const float* __restrict__ node_feats,
    const float* __restrict__ lin1_ws,
    const float* __restrict__ lin1_wv,
    float* __restrict__ y)
{
    __shared__ float xf[16 * 520];
    const int blk = blockIdx.x;      // 625
    const int t = threadIdx.x;
    const int base = blk * 16;

    const float4* nf4 = (const float4*)(node_feats + (size_t)base * 512);
    #pragma unroll
    for (int r = 0; r < 8; r++) {
        int i4 = r * 256 + t;
        int flat = i4 * 4;
        int n = flat >> 9;
        int off = flat & 511;
        *(float4*)&xf[n * 520 + off] = nf4[i4];
    }
    __syncthreads();

    const int n_loc = t >> 4;
    const int w0 = (t & 15) * 8;
    float as[8];
    float av[8][3];
    #pragma unroll
    for (int j = 0; j < 8; j++) { as[j] = 0.f; av[j][0] = 0.f; av[j][1] = 0.f; av[j][2] = 0.f; }

    const float* xrow = &xf[n_loc * 520];
    #pragma unroll 1
    for (int u = 0; u < 128; u++) {
        float xs  = xrow[u];
        float xv0 = xrow[128 + u*3 + 0];
        float xv1 = xrow[128 + u*3 + 1];
        float xv2 = xrow[128 + u*3 + 2];
        float ws[8], wvv[8];
        *(float4*)&ws[0] = *(const float4*)&lin1_ws[u*128 + w0];
        *(float4*)&ws[4] = *(const float4*)&lin1_ws[u*128 + w0 + 4];
        *(float4*)&wvv[0] = *(const float4*)&lin1_wv[u*128 + w0];
        *(float4*)&wvv[4] = *(const float4*)&lin1_wv[u*128 + w0 + 4];
        #pragma unroll
        for (int j = 0; j < 8; j++) {
            as[j]    += xs  * ws[j];
            av[j][0] += xv0 * wvv[j];
            av[j][1] += xv1 * wvv[j];
            av[j][2] += xv2 * wvv[j];
        }
    }

    const float l1 = 0.0883883476483f;  // 1/sqrt(128)
    const int node = base + n_loc;
    float* yrow = y + (size_t)node * 512;
    #pragma unroll
    for (int j = 0; j < 8; j++) {
        float4 o = make_float4(as[j] * l1, av[j][0] * l1, av[j][1] * l1, av[j][2] * l1);
        *(float4*)&yrow[(w0 + j) * 4] = o;
    }
}

// ---------------- CSR build ----------------
__global__ __launch_bounds__(256) void hist_kernel(const int* __restrict__ edge_index,
                                                   int* __restrict__ deg) {
    int e = blockIdx.x * 256 + threadIdx.x;
    if (e < N_EDGES) atomicAdd(&deg[edge_index[e]], 1);
}

__global__ __launch_bounds__(1024) void scan_kernel(const int* __restrict__ deg,
                                                    int* __restrict__ row_start,
                                                    int* __restrict__ cursor) {
    __shared__ int wsum[16];
    __shared__ int carry_s;
    const int t = threadIdx.x;        // 0..1023
    const int lane = t & 63, w = t >> 6;
    if (t == 0) carry_s = 0;
    __syncthreads();
    for (int chunk = 0; chunk < 10; chunk++) {
        int idx = chunk * 1024 + t;
        int v = (idx < N_NODES) ? deg[idx] : 0;
        int x = v;
        #pragma unroll
        for (int off = 1; off < 64; off <<= 1) {
            int yv = __shfl_up(x, off, 64);
            if (lane >= off) x += yv;
        }
        if (lane == 63) wsum[w] = x;
        __syncthreads();
        int wpre = 0;
        for (int i = 0; i < w; i++) wpre += wsum[i];
        int incl = x + wpre + carry_s;
        int excl = incl - v;
        if (idx < N_NODES) { row_start[idx] = excl; cursor[idx] = excl; }
        __syncthreads();
        if (t == 1023) carry_s = incl;
        __syncthreads();
    }
    if (t == 0) row_start[N_NODES] = carry_s;
}

__global__ __launch_bounds__(256) void scatter_kernel(const int* __restrict__ edge_index,
                                                      int* __restrict__ cursor,
                                                      int* __restrict__ edge_list) {
    int e = blockIdx.x * 256 + threadIdx.x;
    if (e < N_EDGES) {
        int pos = atomicAdd(&cursor[edge_index[e]], 1);
        edge_list[pos] = e;
    }
}

// ---------------- pack_w2a: w2/8 -> bf16, MFMA A-fragment order (A = w2^T) ----------------
// slot id = (ks*32 + mf)*64 + lane; value j: w2[k][col]*0.125,
// k = ks*32 + (lane>>4)*8 + j, col = mf*16 + (lane&15)
__global__ __launch_bounds__(256) void pack_w2a_kernel(
    const float* __restrict__ fc_w2, unsigned short* __restrict__ w2a)
{
    int id = blockIdx.x * 256 + threadIdx.x;   // 0..4095
    int lane = id & 63;
    int mfg = (id >> 6) & 31;
    int ks = id >> 11;
    int col = mfg * 16 + (lane & 15);
    int k0 = ks * 32 + (lane >> 4) * 8;
    S8 pk;
    #pragma unroll
    for (int j = 0; j < 8; j++)
        pk.u[j] = f2bf(fc_w2[(k0 + j) * 512 + col] * 0.125f);
    *(uint4*)(w2a + (size_t)id * 8) = pk.q;
}

// ---------------- Kernel B1: edge MLP, layer3 via MFMA -> planar bf16 w ----------------
// w_planes[comp][e][u], comp in {ss, sv, vs, vv}
__global__ __launch_bounds__(256) void edge_w_mfma(
    const float* __restrict__ edge_feats,
    const float* __restrict__ fc_w0,
    const float* __restrict__ fc_w1,
    const unsigned short* __restrict__ w2a,
    unsigned short* __restrict__ w_planes)
{
    __shared__ float ef[64 * 9];
    __shared__ float h0[64 * 68];
    __shared__ unsigned short h1b[64 * 72];

    const int blk = blockIdx.x;      // 2500
    const int t = threadIdx.x;
    const int eb0 = blk * 64;

    // stage edge_feats (64 x 8)
    #pragma unroll
    for (int r = 0; r < 2; r++) {
        int idx = r * 256 + t;
        ef[(idx >> 3) * 9 + (idx & 7)] = edge_feats[(size_t)eb0 * 8 + idx];
    }
    __syncthreads();

    const int e_loc = t >> 2;
    const int c0 = (t & 3) * 16;

    // phase 1: h0 = silu_c(ef @ w0 / sqrt(8))
    {
        float a0[16];
        #pragma unroll
        for (int i = 0; i < 16; i++) a0[i] = 0.f;
        const float* efr = &ef[e_loc * 9];
        #pragma unroll
        for (int k = 0; k < 8; k++) {
            float ek = efr[k];
            float w[16];
            #pragma unroll
            for (int q4 = 0; q4 < 4; q4++)
                *(float4*)&w[q4*4] = *(const float4*)&fc_w0[k*64 + c0 + q4*4];
            #pragma unroll
            for (int i = 0; i < 16; i++) a0[i] += ek * w[i];
        }
        const float is8 = 0.35355339059f;
        #pragma unroll
        for (int i = 0; i < 16; i++)
            h0[e_loc * 68 + c0 + i] = silu_c(a0[i] * is8);
    }
    __syncthreads();

    // phase 2: h1 = silu_c(h0 @ w1 / 8), stored bf16 into h1b[e][k]
    {
        float a1[16];
        #pragma unroll
        for (int i = 0; i < 16; i++) a1[i] = 0.f;
        const float* h0r = &h0[e_loc * 68];
        #pragma unroll 1
        for (int k = 0; k < 64; k++) {
            float hk = h0r[k];
            float w[16];
            #pragma unroll
            for (int q4 = 0; q4 < 4; q4++)
                *(float4*)&w[q4*4] = *(const float4*)&fc_w1[k*64 + c0 + q4*4];
            #pragma unroll
            for (int i = 0; i < 16; i++) a1[i] += hk * w[i];
        }
        S8 p0, p1;
        #pragma unroll
        for (int i = 0; i < 8; i++) {
            p0.u[i] = f2bf(silu_c(a1[i] * 0.125f));
            p1.u[i] = f2bf(silu_c(a1[8 + i] * 0.125f));
        }
        *(uint4*)&h1b[e_loc * 72 + c0]     = p0.q;
        *(uint4*)&h1b[e_loc * 72 + c0 + 8] = p1.q;
    }
    __syncthreads();

    // phase 3: W_block = w2^T(bf16, /8 folded) @ h1^T  via MFMA
    // D[m=outcol][n=edge]; wave wv owns cols wv*128..wv*128+127 -> component wv
    const int lane = t & 63;
    const int wv = t >> 6;
    const int quad = lane >> 4;
    const int m15 = lane & 15;

    floatx4 c[8][4];   // [mf][ef]
    #pragma unroll
    for (int mf = 0; mf < 8; mf++)
        #pragma unroll
        for (int ee = 0; ee < 4; ee++)
            c[mf][ee] = (floatx4){0.f, 0.f, 0.f, 0.f};

    const uint4* w2aq = (const uint4*)w2a;
    #pragma unroll
    for (int ks = 0; ks < 2; ks++) {
        S8 bfr[4];
        #pragma unroll
        for (int ee = 0; ee < 4; ee++)
            bfr[ee].q = *(const uint4*)&h1b[(ee*16 + m15) * 72 + ks*32 + quad*8];
        #pragma unroll
        for (int mf = 0; mf < 8; mf++) {
            S8 afr;
            afr.q = w2aq[(size_t)(ks*32 + wv*8 + mf) * 64 + lane];
            #pragma unroll
            for (int ee = 0; ee < 4; ee++)
                c[mf][ee] = __builtin_amdgcn_mfma_f32_16x16x32_bf16(afr.v, bfr[ee].v, c[mf][ee], 0, 0, 0);
        }
    }

    // epilogue: c[mf][ee][i] = w[col = wv*128 + mf*16 + quad*4 + i][edge = ee*16 + m15]
    unsigned short* plane = w_planes + (size_t)wv * N_EDGES * 128;
    #pragma unroll
    for (int mf = 0; mf < 8; mf++) {
        #pragma unroll
        for (int ee = 0; ee < 4; ee++) {
            int e = eb0 + ee*16 + m15;
            int u0 = mf*16 + quad*4;
            ushort4 pk = make_ushort4(f2bf(c[mf][ee][0]), f2bf(c[mf][ee][1]),
                                      f2bf(c[mf][ee][2]), f2bf(c[mf][ee][3]));
            *(ushort4*)(plane + (size_t)e * 128 + u0) = pk;
        }
    }
}

// ---------------- Kernel B2: per-node gather (no atomics, planar w) ----------------
__global__ __launch_bounds__(256) void gather_kernel(
    const int* __restrict__ row_start,
    const int* __restrict__ edge_list,
    const int* __restrict__ edge_index,
    const float* __restrict__ edge_attrs,
    const unsigned short* __restrict__ w_planes,
    const float* __restrict__ y,
    float* __restrict__ acc)
{
    const int t = threadIdx.x;
    const int half = t >> 7;
    const int u = t & 127;
    const int n = blockIdx.x * 2 + half;   // 5000 blocks
    const int sbeg = row_start[n];
    const int send = row_start[n + 1];

    float aS0 = 0.f, aS1 = 0.f;
    float aV2x = 0.f, aV2y = 0.f, aV2z = 0.f;
    float aV3x = 0.f, aV3y = 0.f, aV3z = 0.f;

    const unsigned short* pss = w_planes;
    const unsigned short* psv = w_planes + (size_t)1 * N_EDGES * 128;
    const unsigned short* pvs = w_planes + (size_t)2 * N_EDGES * 128;
    const unsigned short* pvv = w_planes + (size_t)3 * N_EDGES * 128;

    for (int i = sbeg; i < send; i++) {
        int e = edge_list[i];
        int src = edge_index[N_EDGES + e];
        size_t eo = (size_t)e * 128 + u;
        float wss = bf2f(pss[eo]);
        float wsv = bf2f(psv[eo]);
        float wvs = bf2f(pvs[eo]);
        float wvv = bf2f(pvv[eo]);
        float4 qv = *(const float4*)(y + (size_t)src * 512 + u * 4);
        float4 ea = *(const float4*)(edge_attrs + (size_t)e * 4);
        aS0 += wss * qv.x * ea.x;
        aS1 += wvv * (qv.y*ea.y + qv.z*ea.z + qv.w*ea.w);
        float tsv = wsv * qv.x;
        aV2x += tsv * ea.y; aV2y += tsv * ea.z; aV2z += tsv * ea.w;
        float tvs = wvs * ea.x;
        aV3x += tvs * qv.y; aV3y += tvs * qv.z; aV3z += tvs * qv.w;
    }

    const float inv = 0.25f;                 // 1/sqrt(16)
    const float s1c = 0.57735026919f * 0.25f;
    float* a = acc + (size_t)n * 1024;
    a[u] = aS0 * inv;
    a[128 + u] = aS1 * s1c;
    a[256 + u*3 + 0] = aV2x * inv;
    a[256 + u*3 + 1] = aV2y * inv;
    a[256 + u*3 + 2] = aV2z * inv;
    a[256 + (128 + u)*3 + 0] = aV3x * inv;
    a[256 + (128 + u)*3 + 1] = aV3y * inv;
    a[256 + (128 + u)*3 + 2] = aV3z * inv;
}

// ---------------- pack_b: B matrices -> bf16, MFMA B-fragment order ----------------
__global__ __launch_bounds__(256) void pack_b_kernel(
    const float* __restrict__ sc_ws, const float* __restrict__ lin2_ws,
    const float* __restrict__ sc_wv, const float* __restrict__ lin2_wv,
    unsigned short* __restrict__ b_pre)
{
    int id = blockIdx.x * 256 + threadIdx.x;     // 0..49151
    int mat = id / 24576;
    int slot = id - mat * 24576;
    int ks = slot >> 9;
    int rr = slot & 511;
    int lane = rr & 63;
    int quad = lane >> 4;
    int n = ((rr >> 6) << 4) + (lane & 15);
    const float* sc  = mat ? sc_wv  : sc_ws;
    const float* lin = mat ? lin2_wv : lin2_ws;
    S8 pk;
    #pragma unroll
    for (int j = 0; j < 8; j++) {
        int k = ks * 32 + quad * 8 + j;
        float w;
        if (k < 1280) {
            int u = k & 127, v = k >> 7;
            w = sc[(u * 10 + v) * 128 + n];
        } else {
            w = lin[(k - 1280) * 128 + n];
        }
        pk.u[j] = f2bf(w);
    }
    *(uint4*)(b_pre + (size_t)id * 8) = pk.q;
}

// ---------------- node_out as MFMA GEMM ----------------
__global__ __launch_bounds__(256) void node_out_mfma(
    const float* __restrict__ node_feats,
    const float* __restrict__ node_attrs,
    const float* __restrict__ acc,
    const unsigned short* __restrict__ b_pre,
    float* __restrict__ out)
{
    __shared__ short8x Al[256];     // 64 rows x 32 k, fragment-order packed (4 KB)
    const int bid = blockIdx.x;
    const int t = threadIdx.x;
    const int lane = t & 63;
    const int wv = t >> 6;
    const bool is_s = (bid < SBLK);

    const int r = t >> 2;
    const int q = t & 3;
    int node, comp, st;
    if (is_s) {
        int R = bid * 64 + r;
        node = (R < N_NODES) ? R : 0;
        comp = 0; st = 1;
    } else {
        int Rg = (bid - SBLK) * 64 + r;
        if (Rg >= 3 * N_NODES) Rg = 0;
        comp = Rg / N_NODES;
        node = Rg - comp * N_NODES;
        st = 3;
    }
    const float* px = is_s ? (node_feats + (size_t)node * 512)
                           : (node_feats + (size_t)node * 512 + 128 + comp);
    const float* pa = is_s ? (acc + (size_t)node * 1024)
                           : (acc + (size_t)node * 1024 + 256 + comp);
    const float* pattr = node_attrs + node * 10;

    const int a_slot = ((r >> 4) << 6) + (q << 4) + (r & 15);
    const uint4* bfrag_base = (const uint4*)(b_pre) + (is_s ? 0 : 24576);

    const float sc_norm = 0.02795084972f;   // 1/sqrt(1280)
    const float l2 = 0.0625f;               // 1/sqrt(256)

    floatx4 c[4][2];
    #pragma unroll
    for (int af = 0; af < 4; af++) {
        c[af][0] = (floatx4){0.f, 0.f, 0.f, 0.f};
        c[af][1] = (floatx4){0.f, 0.f, 0.f, 0.f};
    }

    for (int ks = 0; ks < 48; ks++) {
        S8 b0, b1;
        b0.q = bfrag_base[ks*512 + (wv*2+0)*64 + lane];
        b1.q = bfrag_base[ks*512 + (wv*2+1)*64 + lane];

        __syncthreads();
        {
            int k0 = ks * 32 + q * 8;
            S8 pk;
            if (k0 < 1280) {
                int u0 = k0 & 127;
                int v  = k0 >> 7;
                float att = pattr[v] * sc_norm;
                #pragma unroll
                for (int j = 0; j < 8; j++)
                    pk.u[j] = f2bf(px[(u0 + j) * st] * att);
            } else {
                int j2 = k0 - 1280;
                #pragma unroll
                for (int j = 0; j < 8; j++)
                    pk.u[j] = f2bf(pa[(j2 + j) * st] * l2);
            }
            Al[a_slot] = pk.v;
        }
        __syncthreads();

        short8x a0 = Al[lane];
        short8x a1 = Al[64 + lane];
        short8x a2 = Al[128 + lane];
        short8x a3 = Al[192 + lane];
        c[0][0] = __builtin_amdgcn_mfma_f32_16x16x32_bf16(a0, b0.v, c[0][0], 0, 0, 0);
        c[0][1] = __builtin_amdgcn_mfma_f32_16x16x32_bf16(a0, b1.v, c[0][1], 0, 0, 0);
        c[1][0] = __builtin_amdgcn_mfma_f32_16x16x32_bf16(a1, b0.v, c[1][0], 0, 0, 0);
        c[1][1] = __builtin_amdgcn_mfma_f32_16x16x32_bf16(a1, b1.v, c[1][1], 0, 0, 0);
        c[2][0] = __builtin_amdgcn_mfma_f32_16x16x32_bf16(a2, b0.v, c[2][0], 0, 0, 0);
        c[2][1] = __builtin_amdgcn_mfma_f32_16x16x32_bf16(a2, b1.v, c[2][1], 0, 0, 0);
        c[3][0] = __builtin_amdgcn_mfma_f32_16x16x32_bf16(a3, b0.v, c[3][0], 0, 0, 0);
        c[3][1] = __builtin_amdgcn_mfma_f32_16x16x32_bf16(a3, b1.v, c[3][1], 0, 0, 0);
    }

    const int m = lane & 15;
    const int rq = (lane >> 4) * 4;
    if (is_s) {
        const int n0 = bid * 64;
        #pragma unroll
        for (int af = 0; af < 4; af++) {
            #pragma unroll
            for (int i = 0; i < 4; i++) {
                int n = n0 + af*16 + rq + i;
                if (n < N_NODES) {
                    out[(size_t)n*512 + wv*32 + m]      = c[af][0][i];
                    out[(size_t)n*512 + wv*32 + 16 + m] = c[af][1][i];
                }
            }
        }
    } else {
        const int r0 = (bid - SBLK) * 64;
        #pragma unroll
        for (int af = 0; af < 4; af++) {
            #pragma unroll
            for (int i = 0; i < 4; i++) {
                int Rg = r0 + af*16 + rq + i;
                if (Rg < 3 * N_NODES) {
                    int cc = Rg / N_NODES;
                    int nn = Rg - cc * N_NODES;
                    float* po = out + (size_t)nn*512 + 128 + cc;
                    po[(wv*32 + m)*3]      = c[af][0][i];
                    po[(wv*32 + 16 + m)*3] = c[af][1][i];
                }
            }
        }
    }
}

extern "C" void kernel_launch(void* const* d_in, const int* in_sizes, int n_in,
                              void* d_out, int out_size, void* d_ws, size_t ws_size,
                              hipStream_t stream) {
    const float* node_feats = (const float*)d_in[0];
    const float* node_attrs = (const float*)d_in[1];
    const float* edge_feats = (const float*)d_in[2];
    const float* edge_attrs = (const float*)d_in[3];
    const int*   edge_index = (const int*)  d_in[4];
    const float* lin1_ws    = (const float*)d_in[5];
    const float* lin1_wv    = (const float*)d_in[6];
    const float* fc_w0      = (const float*)d_in[7];
    const float* fc_w1      = (const float*)d_in[8];
    const float* fc_w2      = (const float*)d_in[9];
    const float* lin2_ws    = (const float*)d_in[10];
    const float* lin2_wv    = (const float*)d_in[11];
    const float* sc_ws      = (const float*)d_in[12];
    const float* sc_wv      = (const float*)d_in[13];
    float* out = (float*)d_out;

    // workspace layout
    float* y   = (float*)d_ws;                        //  5,120,000 f32
    float* acc = y + (size_t)N_NODES * 512;           // 10,240,000 f32
    unsigned short* w_planes = (unsigned short*)(acc + (size_t)N_NODES * 1024); // 4*160000*128 bf16
    int* deg       = (int*)(w_planes + (size_t)4 * N_EDGES * 128);
    int* row_start = deg + 10016;
    int* cursor    = row_start + 10016;
    int* edge_list = cursor + 10016;
    unsigned short* b_pre = (unsigned short*)(edge_list + N_EDGES); // 2*24576*8 bf16
    unsigned short* w2a   = b_pre + (size_t)2 * 24576 * 8;          // 4096*8 bf16
    const size_t need = (size_t)(5120000 + 10240000) * 4 + (size_t)4 * N_EDGES * 128 * 2
                      + (size_t)(10016 * 3 + N_EDGES) * 4
                      + ((size_t)2 * 24576 * 8 + (size_t)4096 * 8) * 2;
    if (ws_size < need) return;

    hipLaunchKernelGGL(pack_b_kernel, dim3(192), dim3(256), 0, stream,
                       sc_ws, lin2_ws, sc_wv, lin2_wv, b_pre);
    hipLaunchKernelGGL(pack_w2a_kernel, dim3(16), dim3(256), 0, stream, fc_w2, w2a);
    hipLaunchKernelGGL(node_lin1, dim3(625), dim3(256), 0, stream,
                       node_feats, lin1_ws, lin1_wv, y);

    hipMemsetAsync(deg, 0, (size_t)N_NODES * sizeof(int), stream);
    hipLaunchKernelGGL(hist_kernel, dim3(625), dim3(256), 0, stream, edge_index, deg);
    hipLaunchKernelGGL(scan_kernel, dim3(1), dim3(1024), 0, stream, deg, row_start, cursor);
    hipLaunchKernelGGL(scatter_kernel, dim3(625), dim3(256), 0, stream,
                       edge_index, cursor, edge_list);
    hipLaunchKernelGGL(edge_w_mfma, dim3(2500), dim3(256), 0, stream,
                       edge_feats, fc_w0, fc_w1, w2a, w_planes);
    hipLaunchKernelGGL(gather_kernel, dim3(5000), dim3(256), 0, stream,
                       row_start, edge_list, edge_index, edge_attrs, w_planes, y, acc);

    hipLaunchKernelGGL(node_out_mfma, dim3(SBLK + VBLK), dim3(256), 0, stream,
                       node_feats, node_attrs, acc, b_pre, out);
}